// Round 1
// baseline (1337.031 us; speedup 1.0000x reference)
//
#include <hip/hip_runtime.h>
#include <math.h>

#define BATCH 8192
#define KNN   32
#define HDIM  1024

__global__ __launch_bounds__(256) void mu_kernel(
    const int*   __restrict__ vals,
    const float* __restrict__ distances,
    const float* __restrict__ cache_hidden,
    const float* __restrict__ hiddens,
    const float* __restrict__ W1,
    const float* __restrict__ b1,
    const float* __restrict__ W2,
    const float* __restrict__ b2,
    float*       __restrict__ out)
{
    __shared__ float s_cache[HDIM];
    __shared__ float s_x[3 * KNN];   // [0:32) dist | [32:64) distances | [64:96) label_counts
    __shared__ int   s_vals[KNN];

    const int b    = blockIdx.x;
    const int tid  = threadIdx.x;
    const int lane = tid & 63;
    const int wave = tid >> 6;

    // ---- stage cache_hidden[b] (1024 f32 = 256 float4), vals, distances ----
    const float4* cin = (const float4*)(cache_hidden + (size_t)b * HDIM);
    ((float4*)s_cache)[tid] = cin[tid];
    if (tid < KNN) {
        s_vals[tid]      = vals[b * KNN + tid];
        s_x[KNN + tid]   = distances[b * KNN + tid];
    }
    __syncthreads();

    // ---- each wave computes 8 of the 32 L2 distances ----
    const float4* cp = (const float4*)s_cache;
    for (int kk = 0; kk < 8; ++kk) {
        const int k = wave * 8 + kk;
        const float4* hp = (const float4*)(hiddens + ((size_t)b * KNN + k) * HDIM);
        float acc = 0.f;
        #pragma unroll
        for (int it = 0; it < 4; ++it) {
            float4 hv = hp[lane + it * 64];
            float4 cv = cp[lane + it * 64];
            float d0 = cv.x - hv.x, d1 = cv.y - hv.y;
            float d2 = cv.z - hv.z, d3 = cv.w - hv.w;
            acc += d0 * d0 + d1 * d1 + d2 * d2 + d3 * d3;
        }
        #pragma unroll
        for (int d = 32; d >= 1; d >>= 1) acc += __shfl_xor(acc, d, 64);
        if (lane == 0) s_x[k] = sqrtf(acc);
    }

    // ---- wave 0 lanes 0..31: label_counts[j] = #distinct nonzero vals[0..j] ----
    if (wave == 0 && lane < KNN) {
        int v = s_vals[lane];
        int first = (v != 0) ? 1 : 0;
        for (int i = 0; i < lane; ++i)
            if (s_vals[i] == v) first = 0;
        int cnt = first;
        #pragma unroll
        for (int d = 1; d < KNN; d <<= 1) {
            int t = __shfl_up(cnt, d, 64);
            if (lane >= d) cnt += t;
        }
        s_x[2 * KNN + lane] = (float)cnt;
    }
    __syncthreads();

    // ---- wave 0: MLP (lane j = hidden unit j), then write outputs ----
    if (wave == 0) {
        float acc = b1[lane];
        const float* w = W1 + lane * (3 * KNN);
        #pragma unroll 8
        for (int i = 0; i < 3 * KNN; ++i) acc += s_x[i] * w[i];
        float hid = tanhf(acc);
        float p = hid * W2[lane];
        #pragma unroll
        for (int d = 32; d >= 1; d >>= 1) p += __shfl_xor(p, d, 64);
        float mu    = 1.0f / (1.0f + expf(-(p + b2[0])));
        float scale = 5.0f * mu;
        if (lane < KNN) {
            float cd = s_x[lane] * scale;
            out[(size_t)b * KNN + lane] = cd;                                  // context_dist (scaled)
            out[(size_t)BATCH * KNN + (size_t)b * KNN + lane] = s_x[KNN + lane] + cd;  // new_distances
        }
    }
}

extern "C" void kernel_launch(void* const* d_in, const int* in_sizes, int n_in,
                              void* d_out, int out_size, void* d_ws, size_t ws_size,
                              hipStream_t stream) {
    const int*   vals         = (const int*)  d_in[0];
    const float* distances    = (const float*)d_in[1];
    const float* cache_hidden = (const float*)d_in[2];
    const float* hiddens      = (const float*)d_in[3];
    const float* W1           = (const float*)d_in[4];
    const float* b1           = (const float*)d_in[5];
    const float* W2           = (const float*)d_in[6];
    const float* b2           = (const float*)d_in[7];
    float* out = (float*)d_out;

    mu_kernel<<<dim3(BATCH), dim3(256), 0, stream>>>(
        vals, distances, cache_hidden, hiddens, W1, b1, W2, b2, out);
}